// Round 18
// baseline (138.098 us; speedup 1.0000x reference)
//
#include <hip/hip_runtime.h>
#include <hip/hip_fp8.h>
#include <math.h>

#define BSZ   8192
#define NCLS  57
#define DIM   256
#define NTASK 57
#define INV_T (1.0f/0.07f)
#define C2EXP (INV_T * 1.44269504f)   // INV_T * log2(e): exp(sv) = exp2(acc*C2EXP)
#define LN2   0.69314718f
#define GBM   128                // row tiles (64 rows each)
#define GBN   32                 // col tiles (256 cols each)
#define NTILE (GBM * GBN)        // 4096
#define FINB  256                // wide finalize: 256 blocks x 256 thr

typedef float f32x4 __attribute__((ext_vector_type(4)));
typedef long  lgx2  __attribute__((ext_vector_type(2)));

// async global->LDS, 16B per lane; l must be wave-uniform base (HW adds lane*16)
__device__ __forceinline__ void gload_lds16(const void* g, void* l) {
    __builtin_amdgcn_global_load_lds(
        (const __attribute__((address_space(1))) unsigned int*)g,
        (__attribute__((address_space(3))) unsigned int*)l, 16, 0, 0);
}

// ---- kernel 1: fused logits stats + normalize->fp8 (K-interleaved) + hdr zero ------
// fp8 K-layout: k' = (ks>>1)*64 + g*16 + (ks&1)*8 + b for original k = ks*32+g*8+b.
__global__ __launch_bounds__(256) void k_prep(
        const float* __restrict__ logits, const float* __restrict__ emb,
        const int* __restrict__ labels, float* __restrict__ u,
        float* __restrict__ cls_part, unsigned char* __restrict__ e,
        int* __restrict__ hdr) {
    __shared__ float scls[4];
    int wave = threadIdx.x >> 6;
    int lane = threadIdx.x & 63;
    int row  = blockIdx.x * 4 + wave;

    float v = (lane < NCLS) ? logits[row * NCLS + lane] : -3.0e38f;
    float m = v;
    #pragma unroll
    for (int s = 1; s < 64; s <<= 1) m = fmaxf(m, __shfl_xor(m, s));
    float ex = (lane < NCLS) ? __expf(v - m) : 0.0f;
    float se = ex;
    #pragma unroll
    for (int s = 1; s < 64; s <<= 1) se += __shfl_xor(se, s);
    float lse = m + logf(se);
    float p = ex / se;
    float term = (lane < NCLS) ? p * logf(p + 1e-8f) : 0.0f;
    float ent = term;
    #pragma unroll
    for (int s = 1; s < 64; s <<= 1) ent += __shfl_xor(ent, s);
    ent = -ent;
    int lab = labels[row];
    float vl = __shfl(v, lab);
    float cls = lse - vl;

    const float4* src = reinterpret_cast<const float4*>(emb + (size_t)row * DIM);
    float4 x = src[lane];
    float ss = x.x*x.x + x.y*x.y + x.z*x.z + x.w*x.w;
    #pragma unroll
    for (int s = 1; s < 64; s <<= 1) ss += __shfl_xor(ss, s);
    float sc = 1.0f / fmaxf(sqrtf(ss), 1e-12f);
    __hip_fp8_e4m3 f0(x.x * sc), f1(x.y * sc), f2(x.z * sc), f3(x.w * sc);
    uchar4 o;
    o.x = *reinterpret_cast<unsigned char*>(&f0);
    o.y = *reinterpret_cast<unsigned char*>(&f1);
    o.z = *reinterpret_cast<unsigned char*>(&f2);
    o.w = *reinterpret_cast<unsigned char*>(&f3);
    int kp = (lane >> 4) * 64 + ((lane >> 1) & 3) * 16 + ((lane >> 3) & 1) * 8
           + (lane & 1) * 4;
    *reinterpret_cast<uchar4*>(e + (size_t)row * DIM + kp) = o;

    if (lane == 0) {
        u[row] = ent / 4.04305127f;      // log(57)
        scls[wave] = cls;
    }
    // zero header: [0]=ticket [1]=contr_total [2..58]=task_count
    if (blockIdx.x == 0 && threadIdx.x < 64) hdr[threadIdx.x] = 0;
    __syncthreads();
    if (threadIdx.x == 0) cls_part[blockIdx.x] = scls[0] + scls[1] + scls[2] + scls[3];
}

// ---- epilogue accumulate (exp2-folded), specialized on diagonal presence -----------
// Accumulates S in log2 units (scaled by LN2 in finalize).
template<bool HD>
__device__ __forceinline__ void epi_accum(
        const f32x4 (&acc)[2][4], const unsigned char* ts, const int* ctb,
        int m0, int cbase, int h, int g, int lr,
        float (&T)[4], float (&P)[4], float (&S)[4]) {
    #pragma unroll
    for (int m = 0; m < 2; ++m) {
        unsigned rt4 = *reinterpret_cast<const unsigned*>(&ts[h * 32 + m * 16 + g * 4]);
        #pragma unroll
        for (int r = 0; r < 4; ++r) {
            int rt = (rt4 >> (8 * r)) & 255;
            #pragma unroll
            for (int f = 0; f < 4; ++f) {
                float s2 = acc[m][f][r] * C2EXP;     // log2-domain score
                float ev = exp2f(s2);
                bool keep = true;
                if (HD)
                    keep = (m0 + h * 32 + m * 16 + g * 4 + r) != (cbase + f * 16 + lr);
                bool eq = (rt == ctb[f]) && keep;
                T[f] += keep ? ev : 0.0f;
                P[f] += eq ? ev : 0.0f;
                S[f] += eq ? s2 : 0.0f;
            }
        }
    }
}

// ---- kernel 2: 64x256 tiles, wave-tile 32x64, <=64 unified regs -> 8 waves/SIMD ----
// R17 structure, halved wave-tile: acc[2][4]=32 AGPR; B loaded per-(t,f) as one
// transient lgx2 (4 VGPR live, not 16); A from swizzled LDS. launch_bounds(512,8)
// forces the <=64-reg occupancy bin (m69: 32 waves/CU). Plain stores, zero fences;
// publication via kernel boundary. bn==0 blocks histogram their 64 rows.
__global__ __launch_bounds__(512, 8) void k_negsum(
        const unsigned char* __restrict__ E, const int* __restrict__ tasks,
        float* __restrict__ partial, int* __restrict__ task_count) {
    __shared__ unsigned char Asm[64 * 256];    // 16 KB
    __shared__ unsigned char ts[64];
    __shared__ float scr[3][256];

    // XCD swizzle (4096 % 8 == 0 -> bijective)
    int b = (blockIdx.x & 7) * (NTILE / 8) + (blockIdx.x >> 3);
    int bm = b >> 5, bn = b & 31;
    int m0 = bm * 64, n0 = bn * 256;
    bool hasdiag = (bn == (bm >> 2));

    int tid = threadIdx.x;
    int w = tid >> 6, lane = tid & 63;
    int h = w >> 2, cg = w & 3;
    int g = lane >> 4, lr = lane & 15;
    int cbase = n0 + cg * 64;
    const unsigned char* bp = E + (size_t)(cbase + lr) * DIM + g * 16;

    #pragma unroll
    for (int it = 0; it < 2; ++it) {
        int flat = it * 512 + tid;       // 16B chunk 0..1023
        int row = flat >> 4, kb = flat & 15;
        int kbs = kb ^ (row & 7);        // source-side chunk XOR (read applies same)
        gload_lds16(E + (size_t)(m0 + row) * DIM + kbs * 16,
                    Asm + (size_t)(it * 512 + w * 64) * 16);
    }
    if (tid < 64) ts[tid] = (unsigned char)tasks[m0 + tid];
    __syncthreads();
    if (bn == 0 && tid < 64) atomicAdd(&task_count[ts[tid]], 1);

    f32x4 acc[2][4] = {};
    #pragma unroll 1
    for (int t = 0; t < 4; ++t) {
        lgx2 a[2];
        #pragma unroll
        for (int m = 0; m < 2; ++m)
            a[m] = *reinterpret_cast<const lgx2*>(
                Asm + (size_t)(h * 32 + m * 16 + lr) * 256
                    + (((t * 4 + g) ^ (lr & 7)) * 16));
        #pragma unroll
        for (int f = 0; f < 4; ++f) {
            lgx2 bc = *reinterpret_cast<const lgx2*>(
                bp + (size_t)f * 16 * DIM + t * 64);
            #pragma unroll
            for (int m = 0; m < 2; ++m) {
                acc[m][f] = __builtin_amdgcn_mfma_f32_16x16x32_fp8_fp8(
                    a[m][0], bc[0], acc[m][f], 0, 0, 0);
                acc[m][f] = __builtin_amdgcn_mfma_f32_16x16x32_fp8_fp8(
                    a[m][1], bc[1], acc[m][f], 0, 0, 0);
            }
        }
    }

    int ctb[4];
    #pragma unroll
    for (int f = 0; f < 4; ++f) ctb[f] = tasks[cbase + f * 16 + lr];
    float T[4] = {}, P[4] = {}, S[4] = {};
    if (hasdiag) epi_accum<true >(acc, ts, ctb, m0, cbase, h, g, lr, T, P, S);
    else         epi_accum<false>(acc, ts, ctb, m0, cbase, h, g, lr, T, P, S);

    #pragma unroll
    for (int f = 0; f < 4; ++f) {        // cross-g butterfly: 2 shfl per quantity
        T[f] += __shfl_xor(T[f], 16); T[f] += __shfl_xor(T[f], 32);
        P[f] += __shfl_xor(P[f], 16); P[f] += __shfl_xor(P[f], 32);
        S[f] += __shfl_xor(S[f], 16); S[f] += __shfl_xor(S[f], 32);
    }
    if (h == 1 && g == 0) {
        #pragma unroll
        for (int f = 0; f < 4; ++f) {
            int c = cg * 64 + f * 16 + lr;
            scr[0][c] = T[f]; scr[1][c] = P[f]; scr[2][c] = S[f];
        }
    }
    __syncthreads();
    if (h == 0 && g == 0) {              // plain coalesced unique-writer stores
        #pragma unroll
        for (int f = 0; f < 4; ++f) {
            int c = cg * 64 + f * 16 + lr;
            size_t sl = (size_t)bm * BSZ + n0 + c;
            partial[sl]                         = T[f] + scr[0][c];
            partial[(size_t)GBM * BSZ + sl]     = P[f] + scr[1][c];
            partial[(size_t)2 * GBM * BSZ + sl] = S[f] + scr[2][c];
        }
    }
}

// ---- kernel 3: WIDE finalize (256 blocks x 256 thr) + ticket combine ---------------
// Block b owns cols [b*32, b*32+32); 8 threads/col each sum 16 bm-partials
// (coalesced), LDS-combine, per-col contr via first-order expansion (S in log2
// units -> x LN2), one atomicAdd + ticket; 256th block emits the scalar.
__global__ __launch_bounds__(256) void k_finalize(
        const int* __restrict__ tasks, const int* __restrict__ task_count,
        const float* __restrict__ partial, const float* __restrict__ u,
        const float* __restrict__ cls_part, int* __restrict__ hdr,
        float* __restrict__ out) {
    __shared__ float sT[8][32], sP[8][32], sS[8][32];
    __shared__ float redf[4]; __shared__ long long redn[4];
    __shared__ int lastflag;

    int* ticket = hdr;
    float* contr_total = (float*)(hdr + 1);

    int tid = threadIdx.x;
    int c = tid & 31, q = tid >> 5;      // 8 bm-groups x 32 cols
    int j = blockIdx.x * 32 + c;

    float T = 0.0f, P = 0.0f, S = 0.0f;
    #pragma unroll
    for (int k = 0; k < 16; ++k) {
        int bm = q * 16 + k;
        size_t sl = (size_t)bm * BSZ + j;
        T += partial[sl];
        P += partial[(size_t)GBM * BSZ + sl];
        S += partial[(size_t)2 * GBM * BSZ + sl];
    }
    sT[q][c] = T; sP[q][c] = P; sS[q][c] = S;
    __syncthreads();

    if (tid < 32) {
        #pragma unroll
        for (int qq = 1; qq < 8; ++qq) {
            T = (qq == 1 ? sT[0][tid] : T) + sT[qq][tid];
            P = (qq == 1 ? sP[0][tid] : P) + sP[qq][tid];
            S = (qq == 1 ? sS[0][tid] : S) + sS[qq][tid];
        }
        int jj = blockIdx.x * 32 + tid;
        int cc = task_count[tasks[jj]];
        float v = 0.0f;
        if (cc >= 2 && cc < BSZ) {
            float C = (T - P) + 1e-8f;
            v = u[jj] * ((float)(cc - 1) * logf(C) + P / C - S * LN2);
        }
        #pragma unroll
        for (int s = 1; s < 32; s <<= 1) v += __shfl_xor(v, s);
        if (tid == 0) {
            atomicAdd(contr_total, v);
            __threadfence();             // one tid0 fence per tiny block: cheap
            lastflag = (__hip_atomic_fetch_add(ticket, 1, __ATOMIC_ACQ_REL,
                                               __HIP_MEMORY_SCOPE_AGENT) == FINB - 1);
        }
    }
    __syncthreads();
    if (!lastflag) return;
    __threadfence();                     // acquire: all contr adds visible

    float cl = 0.0f;
    for (int i = tid; i < BSZ / 4; i += 256) cl += cls_part[i];
    long long cn = 0;
    if (tid < NTASK) {
        int cc = task_count[tid];
        if (cc >= 2 && cc < BSZ) cn = (long long)cc * (cc - 1);
    }
    #pragma unroll
    for (int s = 1; s < 64; s <<= 1) { cl += __shfl_xor(cl, s); cn += __shfl_xor(cn, s); }
    int w = tid >> 6, lane = tid & 63;
    if (lane == 0) { redf[w] = cl; redn[w] = cn; }
    __syncthreads();
    if (tid == 0) {
        float ct = 0.0f; long long cnt = 0;
        #pragma unroll
        for (int qq = 0; qq < 4; ++qq) { ct += redf[qq]; cnt += redn[qq]; }
        float con = __hip_atomic_load(contr_total, __ATOMIC_ACQUIRE,
                                      __HIP_MEMORY_SCOPE_AGENT);
        out[0] = 0.7f * (ct / (float)BSZ)
               + 0.3f * (cnt > 0 ? con / (float)cnt : 0.0f);
    }
}

extern "C" void kernel_launch(void* const* d_in, const int* in_sizes, int n_in,
                              void* d_out, int out_size, void* d_ws, size_t ws_size,
                              hipStream_t stream) {
    const float* logits = (const float*)d_in[0];
    const float* emb    = (const float*)d_in[1];
    const int*   labels = (const int*)d_in[2];
    const int*   tasks  = (const int*)d_in[3];
    float* out = (float*)d_out;

    char* ws = (char*)d_ws;
    // layout (4B units):
    // hdr[64]: [0]=ticket [1]=contr_total [2..58]=task_count
    // u[BSZ], cls_part[2048], partial[3*GBM*BSZ] (12 MB), E fp8[BSZ*DIM] (2 MB)
    int*   hdr      = (int*)ws;
    int*   task_cnt = hdr + 2;
    float* u        = (float*)ws + 64;
    float* cls_part = u + BSZ;
    float* partial  = cls_part + 2048;
    unsigned char* e = (unsigned char*)(partial + (size_t)3 * GBM * BSZ);

    // 3 nodes; publication via kernel boundaries (the only cheap device-wide release)
    k_prep    <<<BSZ / 4, 256, 0, stream>>>(logits, emb, labels, u, cls_part, e, hdr);
    k_negsum  <<<NTILE,   512, 0, stream>>>(e, tasks, partial, task_cnt);
    k_finalize<<<FINB,    256, 0, stream>>>(tasks, task_cnt, partial, u, cls_part,
                                            hdr, out);
}

// Round 19
// 91.358 us; speedup vs baseline: 1.5116x; 1.5116x over previous
//
#include <hip/hip_runtime.h>
#include <hip/hip_fp8.h>
#include <math.h>

#define BSZ   8192
#define NCLS  57
#define DIM   256
#define NTASK 57
#define INV_T (1.0f/0.07f)
#define C2EXP (INV_T * 1.44269504f)   // INV_T*log2(e): exp(s) = exp2(acc*C2EXP)
#define LN2   0.69314718f
#define GBM   64                 // row tiles (128 rows each)
#define GBN   32                 // col tiles (256 cols each)
#define NTILE (GBM * GBN)        // 2048
#define FINB  256                // wide finalize: 256 blocks x 256 thr

typedef float f32x4 __attribute__((ext_vector_type(4)));
typedef long  lgx2  __attribute__((ext_vector_type(2)));

// async global->LDS, 16B per lane; l must be wave-uniform base (HW adds lane*16)
__device__ __forceinline__ void gload_lds16(const void* g, void* l) {
    __builtin_amdgcn_global_load_lds(
        (const __attribute__((address_space(1))) unsigned int*)g,
        (__attribute__((address_space(3))) unsigned int*)l, 16, 0, 0);
}

// ---- kernel 1: fused logits stats + normalize->fp8 (K-interleaved) + hdr zero ------
// fp8 K-layout: k' = (ks>>1)*64 + g*16 + (ks&1)*8 + b for original k = ks*32+g*8+b.
__global__ __launch_bounds__(256) void k_prep(
        const float* __restrict__ logits, const float* __restrict__ emb,
        const int* __restrict__ labels, float* __restrict__ u,
        float* __restrict__ cls_part, unsigned char* __restrict__ e,
        int* __restrict__ hdr) {
    __shared__ float scls[4];
    int wave = threadIdx.x >> 6;
    int lane = threadIdx.x & 63;
    int row  = blockIdx.x * 4 + wave;

    float v = (lane < NCLS) ? logits[row * NCLS + lane] : -3.0e38f;
    float m = v;
    #pragma unroll
    for (int s = 1; s < 64; s <<= 1) m = fmaxf(m, __shfl_xor(m, s));
    float ex = (lane < NCLS) ? __expf(v - m) : 0.0f;
    float se = ex;
    #pragma unroll
    for (int s = 1; s < 64; s <<= 1) se += __shfl_xor(se, s);
    float lse = m + logf(se);
    float p = ex / se;
    float term = (lane < NCLS) ? p * logf(p + 1e-8f) : 0.0f;
    float ent = term;
    #pragma unroll
    for (int s = 1; s < 64; s <<= 1) ent += __shfl_xor(ent, s);
    ent = -ent;
    int lab = labels[row];
    float vl = __shfl(v, lab);
    float cls = lse - vl;

    const float4* src = reinterpret_cast<const float4*>(emb + (size_t)row * DIM);
    float4 x = src[lane];
    float ss = x.x*x.x + x.y*x.y + x.z*x.z + x.w*x.w;
    #pragma unroll
    for (int s = 1; s < 64; s <<= 1) ss += __shfl_xor(ss, s);
    float sc = 1.0f / fmaxf(sqrtf(ss), 1e-12f);
    __hip_fp8_e4m3 f0(x.x * sc), f1(x.y * sc), f2(x.z * sc), f3(x.w * sc);
    uchar4 o;
    o.x = *reinterpret_cast<unsigned char*>(&f0);
    o.y = *reinterpret_cast<unsigned char*>(&f1);
    o.z = *reinterpret_cast<unsigned char*>(&f2);
    o.w = *reinterpret_cast<unsigned char*>(&f3);
    int kp = (lane >> 4) * 64 + ((lane >> 1) & 3) * 16 + ((lane >> 3) & 1) * 8
           + (lane & 1) * 4;
    *reinterpret_cast<uchar4*>(e + (size_t)row * DIM + kp) = o;

    if (lane == 0) {
        u[row] = ent / 4.04305127f;      // log(57)
        scls[wave] = cls;
    }
    // zero header: [0]=ticket [1]=contr_total [2..58]=task_count
    if (blockIdx.x == 0 && threadIdx.x < 64) hdr[threadIdx.x] = 0;
    __syncthreads();
    if (threadIdx.x == 0) cls_part[blockIdx.x] = scls[0] + scls[1] + scls[2] + scls[3];
}

// ---- epilogue accumulate (exp2-domain), specialized on diagonal presence -----------
// S accumulated in log2 units (scaled by LN2 in finalize).
template<bool HD>
__device__ __forceinline__ void epi_accum(
        const f32x4 (&acc)[4][4], const unsigned char* ts, const int* ctb,
        int m0, int cbase, int h, int g, int lr,
        float (&T)[4], float (&P)[4], float (&S)[4]) {
    #pragma unroll
    for (int m = 0; m < 4; ++m) {
        unsigned rt4 = *reinterpret_cast<const unsigned*>(&ts[h * 64 + m * 16 + g * 4]);
        #pragma unroll
        for (int r = 0; r < 4; ++r) {
            int rt = (rt4 >> (8 * r)) & 255;
            #pragma unroll
            for (int f = 0; f < 4; ++f) {
                float s2 = acc[m][f][r] * C2EXP;     // log2-domain score
                float ev = exp2f(s2);
                bool keep = true;
                if (HD)
                    keep = (m0 + h * 64 + m * 16 + g * 4 + r) != (cbase + f * 16 + lr);
                bool eq = (rt == ctb[f]) && keep;
                T[f] += keep ? ev : 0.0f;
                P[f] += eq ? ev : 0.0f;
                S[f] += eq ? s2 : 0.0f;
            }
        }
    }
}

// ---- kernel 2: R17 GEMM verbatim + s_setprio around MFMA cluster -------------------
// Plain stores, ZERO fences, publication via kernel boundary (R17: 51us measured).
// K-loop has no inter-wave barriers -> independent-wave regime where setprio
// measured +4-7% (m191), not the lockstep-null case (m190).
__global__ __launch_bounds__(512, 2) void k_negsum(
        const unsigned char* __restrict__ E, const int* __restrict__ tasks,
        float* __restrict__ partial, int* __restrict__ task_count) {
    __shared__ unsigned char Asm[128 * 256];   // 32 KB
    __shared__ unsigned char ts[128];
    __shared__ float scr[3][256];

    // XCD swizzle (2048 % 8 == 0 -> bijective)
    int b = (blockIdx.x & 7) * (NTILE / 8) + (blockIdx.x >> 3);
    int bm = b >> 5, bn = b & 31;
    int m0 = bm * 128, n0 = bn * 256;
    bool hasdiag = (bn == (bm >> 1));

    int tid = threadIdx.x;
    int w = tid >> 6, lane = tid & 63;
    int h = w >> 2, cg = w & 3;
    int g = lane >> 4, lr = lane & 15;
    int cbase = n0 + cg * 64;
    const unsigned char* bp = E + (size_t)(cbase + lr) * DIM + g * 16;

    lgx2 bc[4];
    #pragma unroll
    for (int f = 0; f < 4; ++f)
        bc[f] = *reinterpret_cast<const lgx2*>(bp + (size_t)f * 16 * DIM);

    #pragma unroll
    for (int it = 0; it < 4; ++it) {
        int flat = it * 512 + tid;
        int row = flat >> 4, kb = flat & 15;
        int kbs = kb ^ (row & 7);
        gload_lds16(E + (size_t)(m0 + row) * DIM + kbs * 16,
                    Asm + (size_t)(it * 512 + w * 64) * 16);
    }
    if (tid < 128) ts[tid] = (unsigned char)tasks[m0 + tid];
    __syncthreads();
    if (bn == 0 && tid < 128) atomicAdd(&task_count[ts[tid]], 1);

    f32x4 acc[4][4] = {};
    #pragma unroll 1
    for (int t = 0; t < 4; ++t) {
        lgx2 bn_[4];
        if (t < 3) {
            #pragma unroll
            for (int f = 0; f < 4; ++f)
                bn_[f] = *reinterpret_cast<const lgx2*>(
                    bp + (size_t)f * 16 * DIM + (t + 1) * 64);
        }
        lgx2 a[4];
        #pragma unroll
        for (int m = 0; m < 4; ++m)
            a[m] = *reinterpret_cast<const lgx2*>(
                Asm + (size_t)(h * 64 + m * 16 + lr) * 256
                    + (((t * 4 + g) ^ (lr & 7)) * 16));
        __builtin_amdgcn_s_setprio(1);
        #pragma unroll
        for (int m = 0; m < 4; ++m)
            #pragma unroll
            for (int f = 0; f < 4; ++f) {
                acc[m][f] = __builtin_amdgcn_mfma_f32_16x16x32_fp8_fp8(
                    a[m][0], bc[f][0], acc[m][f], 0, 0, 0);
                acc[m][f] = __builtin_amdgcn_mfma_f32_16x16x32_fp8_fp8(
                    a[m][1], bc[f][1], acc[m][f], 0, 0, 0);
            }
        __builtin_amdgcn_s_setprio(0);
        if (t < 3) {
            #pragma unroll
            for (int f = 0; f < 4; ++f) bc[f] = bn_[f];
        }
    }

    int ctb[4];
    #pragma unroll
    for (int f = 0; f < 4; ++f) ctb[f] = tasks[cbase + f * 16 + lr];
    float T[4] = {}, P[4] = {}, S[4] = {};
    if (hasdiag) epi_accum<true >(acc, ts, ctb, m0, cbase, h, g, lr, T, P, S);
    else         epi_accum<false>(acc, ts, ctb, m0, cbase, h, g, lr, T, P, S);

    #pragma unroll
    for (int f = 0; f < 4; ++f) {        // cross-g butterfly: 2 shfl per quantity
        T[f] += __shfl_xor(T[f], 16); T[f] += __shfl_xor(T[f], 32);
        P[f] += __shfl_xor(P[f], 16); P[f] += __shfl_xor(P[f], 32);
        S[f] += __shfl_xor(S[f], 16); S[f] += __shfl_xor(S[f], 32);
    }
    if (h == 1 && g == 0) {
        #pragma unroll
        for (int f = 0; f < 4; ++f) {
            int c = cg * 64 + f * 16 + lr;
            scr[0][c] = T[f]; scr[1][c] = P[f]; scr[2][c] = S[f];
        }
    }
    __syncthreads();
    if (h == 0 && g == 0) {              // plain coalesced unique-writer stores
        #pragma unroll
        for (int f = 0; f < 4; ++f) {
            int c = cg * 64 + f * 16 + lr;
            size_t sl = (size_t)bm * BSZ + n0 + c;
            partial[sl]                         = T[f] + scr[0][c];
            partial[(size_t)GBM * BSZ + sl]     = P[f] + scr[1][c];
            partial[(size_t)2 * GBM * BSZ + sl] = S[f] + scr[2][c];
        }
    }
}

// ---- kernel 3: WIDE finalize (256 blocks x 256 thr) + ticket combine ---------------
__global__ __launch_bounds__(256) void k_finalize(
        const int* __restrict__ tasks, const int* __restrict__ task_count,
        const float* __restrict__ partial, const float* __restrict__ u,
        const float* __restrict__ cls_part, int* __restrict__ hdr,
        float* __restrict__ out) {
    __shared__ float sT[8][32], sP[8][32], sS[8][32];
    __shared__ float redf[4]; __shared__ long long redn[4];
    __shared__ int lastflag;

    int* ticket = hdr;
    float* contr_total = (float*)(hdr + 1);

    int tid = threadIdx.x;
    int c = tid & 31, q = tid >> 5;      // 8 bm-groups x 32 cols
    int j = blockIdx.x * 32 + c;

    float T = 0.0f, P = 0.0f, S = 0.0f;
    #pragma unroll
    for (int k = 0; k < 8; ++k) {
        int bm = q * 8 + k;
        size_t sl = (size_t)bm * BSZ + j;
        T += partial[sl];
        P += partial[(size_t)GBM * BSZ + sl];
        S += partial[(size_t)2 * GBM * BSZ + sl];
    }
    sT[q][c] = T; sP[q][c] = P; sS[q][c] = S;
    __syncthreads();

    if (tid < 32) {
        #pragma unroll
        for (int qq = 1; qq < 8; ++qq) {
            T = (qq == 1 ? sT[0][tid] : T) + sT[qq][tid];
            P = (qq == 1 ? sP[0][tid] : P) + sP[qq][tid];
            S = (qq == 1 ? sS[0][tid] : S) + sS[qq][tid];
        }
        int jj = blockIdx.x * 32 + tid;
        int cc = task_count[tasks[jj]];
        float v = 0.0f;
        if (cc >= 2 && cc < BSZ) {
            float C = (T - P) + 1e-8f;
            v = u[jj] * ((float)(cc - 1) * logf(C) + P / C - S * LN2);
        }
        #pragma unroll
        for (int s = 1; s < 32; s <<= 1) v += __shfl_xor(v, s);
        if (tid == 0) {
            atomicAdd(contr_total, v);
            __threadfence();             // one tid0 fence per tiny block: cheap
            lastflag = (__hip_atomic_fetch_add(ticket, 1, __ATOMIC_ACQ_REL,
                                               __HIP_MEMORY_SCOPE_AGENT) == FINB - 1);
        }
    }
    __syncthreads();
    if (!lastflag) return;
    __threadfence();                     // acquire: all contr adds visible

    float cl = 0.0f;
    for (int i = tid; i < BSZ / 4; i += 256) cl += cls_part[i];
    long long cn = 0;
    if (tid < NTASK) {
        int cc = task_count[tid];
        if (cc >= 2 && cc < BSZ) cn = (long long)cc * (cc - 1);
    }
    #pragma unroll
    for (int s = 1; s < 64; s <<= 1) { cl += __shfl_xor(cl, s); cn += __shfl_xor(cn, s); }
    int w = tid >> 6, lane = tid & 63;
    if (lane == 0) { redf[w] = cl; redn[w] = cn; }
    __syncthreads();
    if (tid == 0) {
        float ct = 0.0f; long long cnt = 0;
        #pragma unroll
        for (int qq = 0; qq < 4; ++qq) { ct += redf[qq]; cnt += redn[qq]; }
        float con = __hip_atomic_load(contr_total, __ATOMIC_ACQUIRE,
                                      __HIP_MEMORY_SCOPE_AGENT);
        out[0] = 0.7f * (ct / (float)BSZ)
               + 0.3f * (cnt > 0 ? con / (float)cnt : 0.0f);
    }
}

extern "C" void kernel_launch(void* const* d_in, const int* in_sizes, int n_in,
                              void* d_out, int out_size, void* d_ws, size_t ws_size,
                              hipStream_t stream) {
    const float* logits = (const float*)d_in[0];
    const float* emb    = (const float*)d_in[1];
    const int*   labels = (const int*)d_in[2];
    const int*   tasks  = (const int*)d_in[3];
    float* out = (float*)d_out;

    char* ws = (char*)d_ws;
    // layout (4B units):
    // hdr[64]: [0]=ticket [1]=contr_total [2..58]=task_count
    // u[BSZ], cls_part[2048], partial[3*GBM*BSZ] (6 MB), E fp8[BSZ*DIM] (2 MB)
    int*   hdr      = (int*)ws;
    int*   task_cnt = hdr + 2;
    float* u        = (float*)ws + 64;
    float* cls_part = u + BSZ;
    float* partial  = cls_part + 2048;
    unsigned char* e = (unsigned char*)(partial + (size_t)3 * GBM * BSZ);

    // 3 nodes; publication via kernel boundaries (the only cheap device-wide release)
    k_prep    <<<BSZ / 4, 256, 0, stream>>>(logits, emb, labels, u, cls_part, e, hdr);
    k_negsum  <<<NTILE,   512, 0, stream>>>(e, tasks, partial, task_cnt);
    k_finalize<<<FINB,    256, 0, stream>>>(tasks, task_cnt, partial, u, cls_part,
                                            hdr, out);
}

// Round 20
// 71.841 us; speedup vs baseline: 1.9223x; 1.2717x over previous
//
#include <hip/hip_runtime.h>
#include <hip/hip_fp8.h>
#include <math.h>

#define BSZ   8192
#define NCLS  57
#define DIM   256
#define NTASK 57
#define INV_T (1.0f/0.07f)
#define GBM   64                 // row tiles (128 rows each)
#define GBN   32                 // col tiles (256 cols each)
#define NTILE (GBM * GBN)        // 2048
#define FINB  256                // wide finalize: 256 blocks x 256 thr

typedef float f32x4 __attribute__((ext_vector_type(4)));
typedef long  lgx2  __attribute__((ext_vector_type(2)));

// async global->LDS, 16B per lane; l must be wave-uniform base (HW adds lane*16)
__device__ __forceinline__ void gload_lds16(const void* g, void* l) {
    __builtin_amdgcn_global_load_lds(
        (const __attribute__((address_space(1))) unsigned int*)g,
        (__attribute__((address_space(3))) unsigned int*)l, 16, 0, 0);
}

// ---- kernel 1: fused logits stats + normalize->fp8 (K-interleaved) + hdr zero ------
// fp8 K-layout: k' = (ks>>1)*64 + g*16 + (ks&1)*8 + b for original k = ks*32+g*8+b.
__global__ __launch_bounds__(256) void k_prep(
        const float* __restrict__ logits, const float* __restrict__ emb,
        const int* __restrict__ labels, float* __restrict__ u,
        float* __restrict__ cls_part, unsigned char* __restrict__ e,
        int* __restrict__ hdr) {
    __shared__ float scls[4];
    int wave = threadIdx.x >> 6;
    int lane = threadIdx.x & 63;
    int row  = blockIdx.x * 4 + wave;

    float v = (lane < NCLS) ? logits[row * NCLS + lane] : -3.0e38f;
    float m = v;
    #pragma unroll
    for (int s = 1; s < 64; s <<= 1) m = fmaxf(m, __shfl_xor(m, s));
    float ex = (lane < NCLS) ? __expf(v - m) : 0.0f;
    float se = ex;
    #pragma unroll
    for (int s = 1; s < 64; s <<= 1) se += __shfl_xor(se, s);
    float lse = m + logf(se);
    float p = ex / se;
    float term = (lane < NCLS) ? p * logf(p + 1e-8f) : 0.0f;
    float ent = term;
    #pragma unroll
    for (int s = 1; s < 64; s <<= 1) ent += __shfl_xor(ent, s);
    ent = -ent;
    int lab = labels[row];
    float vl = __shfl(v, lab);
    float cls = lse - vl;

    const float4* src = reinterpret_cast<const float4*>(emb + (size_t)row * DIM);
    float4 x = src[lane];
    float ss = x.x*x.x + x.y*x.y + x.z*x.z + x.w*x.w;
    #pragma unroll
    for (int s = 1; s < 64; s <<= 1) ss += __shfl_xor(ss, s);
    float sc = 1.0f / fmaxf(sqrtf(ss), 1e-12f);
    __hip_fp8_e4m3 f0(x.x * sc), f1(x.y * sc), f2(x.z * sc), f3(x.w * sc);
    uchar4 o;
    o.x = *reinterpret_cast<unsigned char*>(&f0);
    o.y = *reinterpret_cast<unsigned char*>(&f1);
    o.z = *reinterpret_cast<unsigned char*>(&f2);
    o.w = *reinterpret_cast<unsigned char*>(&f3);
    int kp = (lane >> 4) * 64 + ((lane >> 1) & 3) * 16 + ((lane >> 3) & 1) * 8
           + (lane & 1) * 4;
    *reinterpret_cast<uchar4*>(e + (size_t)row * DIM + kp) = o;

    if (lane == 0) {
        u[row] = ent / 4.04305127f;      // log(57)
        scls[wave] = cls;
    }
    // zero header: [0]=ticket [1]=contr_total [2..58]=task_count
    if (blockIdx.x == 0 && threadIdx.x < 64) hdr[threadIdx.x] = 0;
    __syncthreads();
    if (threadIdx.x == 0) cls_part[blockIdx.x] = scls[0] + scls[1] + scls[2] + scls[3];
}

// ---- epilogue accumulate, specialized on diagonal presence -------------------------
template<bool HD>
__device__ __forceinline__ void epi_accum(
        const f32x4 (&acc)[4][4], const unsigned char* ts, const int* ctb,
        int m0, int cbase, int h, int g, int lr,
        float (&T)[4], float (&P)[4], float (&S)[4]) {
    #pragma unroll
    for (int m = 0; m < 4; ++m) {
        unsigned rt4 = *reinterpret_cast<const unsigned*>(&ts[h * 64 + m * 16 + g * 4]);
        #pragma unroll
        for (int r = 0; r < 4; ++r) {
            int rt = (rt4 >> (8 * r)) & 255;
            #pragma unroll
            for (int f = 0; f < 4; ++f) {
                float sv = acc[m][f][r] * INV_T;
                float ev = __expf(sv);
                bool keep = true;
                if (HD)
                    keep = (m0 + h * 64 + m * 16 + g * 4 + r) != (cbase + f * 16 + lr);
                bool eq = (rt == ctb[f]) && keep;
                T[f] += keep ? ev : 0.0f;
                P[f] += eq ? ev : 0.0f;
                S[f] += eq ? sv : 0.0f;
            }
        }
    }
}

// ---- kernel 2: R12/R17 GEMM — plain stores, ZERO fences, ZERO tickets --------------
// (R17 measured: 51us, VGPR 64 + 64 AGPR = exactly the 128-reg bin -> 2 blocks/CU.
// ANY addition costing >0 VGPR crosses the cliff and loses 40% — R19 lesson.)
// Publication to k_finalize is the kernel boundary (only cheap device-wide release).
// bn==0 blocks additionally histogram their 128 rows into task_count.
__global__ __launch_bounds__(512, 2) void k_negsum(
        const unsigned char* __restrict__ E, const int* __restrict__ tasks,
        float* __restrict__ partial, int* __restrict__ task_count) {
    __shared__ unsigned char Asm[128 * 256];   // 32 KB
    __shared__ unsigned char ts[128];
    __shared__ float scr[3][256];

    // XCD swizzle (2048 % 8 == 0 -> bijective)
    int b = (blockIdx.x & 7) * (NTILE / 8) + (blockIdx.x >> 3);
    int bm = b >> 5, bn = b & 31;
    int m0 = bm * 128, n0 = bn * 256;
    bool hasdiag = (bn == (bm >> 1));

    int tid = threadIdx.x;
    int w = tid >> 6, lane = tid & 63;
    int h = w >> 2, cg = w & 3;
    int g = lane >> 4, lr = lane & 15;
    int cbase = n0 + cg * 64;
    const unsigned char* bp = E + (size_t)(cbase + lr) * DIM + g * 16;

    lgx2 bc[4];
    #pragma unroll
    for (int f = 0; f < 4; ++f)
        bc[f] = *reinterpret_cast<const lgx2*>(bp + (size_t)f * 16 * DIM);

    #pragma unroll
    for (int it = 0; it < 4; ++it) {
        int flat = it * 512 + tid;
        int row = flat >> 4, kb = flat & 15;
        int kbs = kb ^ (row & 7);
        gload_lds16(E + (size_t)(m0 + row) * DIM + kbs * 16,
                    Asm + (size_t)(it * 512 + w * 64) * 16);
    }
    if (tid < 128) ts[tid] = (unsigned char)tasks[m0 + tid];
    __syncthreads();
    if (bn == 0 && tid < 128) atomicAdd(&task_count[ts[tid]], 1);

    f32x4 acc[4][4] = {};
    #pragma unroll 1
    for (int t = 0; t < 4; ++t) {
        lgx2 bn_[4];
        if (t < 3) {
            #pragma unroll
            for (int f = 0; f < 4; ++f)
                bn_[f] = *reinterpret_cast<const lgx2*>(
                    bp + (size_t)f * 16 * DIM + (t + 1) * 64);
        }
        lgx2 a[4];
        #pragma unroll
        for (int m = 0; m < 4; ++m)
            a[m] = *reinterpret_cast<const lgx2*>(
                Asm + (size_t)(h * 64 + m * 16 + lr) * 256
                    + (((t * 4 + g) ^ (lr & 7)) * 16));
        #pragma unroll
        for (int m = 0; m < 4; ++m)
            #pragma unroll
            for (int f = 0; f < 4; ++f) {
                acc[m][f] = __builtin_amdgcn_mfma_f32_16x16x32_fp8_fp8(
                    a[m][0], bc[f][0], acc[m][f], 0, 0, 0);
                acc[m][f] = __builtin_amdgcn_mfma_f32_16x16x32_fp8_fp8(
                    a[m][1], bc[f][1], acc[m][f], 0, 0, 0);
            }
        if (t < 3) {
            #pragma unroll
            for (int f = 0; f < 4; ++f) bc[f] = bn_[f];
        }
    }

    int ctb[4];
    #pragma unroll
    for (int f = 0; f < 4; ++f) ctb[f] = tasks[cbase + f * 16 + lr];
    float T[4] = {}, P[4] = {}, S[4] = {};
    if (hasdiag) epi_accum<true >(acc, ts, ctb, m0, cbase, h, g, lr, T, P, S);
    else         epi_accum<false>(acc, ts, ctb, m0, cbase, h, g, lr, T, P, S);

    #pragma unroll
    for (int f = 0; f < 4; ++f) {        // cross-g butterfly: 2 shfl per quantity
        T[f] += __shfl_xor(T[f], 16); T[f] += __shfl_xor(T[f], 32);
        P[f] += __shfl_xor(P[f], 16); P[f] += __shfl_xor(P[f], 32);
        S[f] += __shfl_xor(S[f], 16); S[f] += __shfl_xor(S[f], 32);
    }
    if (h == 1 && g == 0) {
        #pragma unroll
        for (int f = 0; f < 4; ++f) {
            int c = cg * 64 + f * 16 + lr;
            scr[0][c] = T[f]; scr[1][c] = P[f]; scr[2][c] = S[f];
        }
    }
    __syncthreads();
    if (h == 0 && g == 0) {              // plain coalesced unique-writer stores
        #pragma unroll
        for (int f = 0; f < 4; ++f) {
            int c = cg * 64 + f * 16 + lr;
            size_t sl = (size_t)bm * BSZ + n0 + c;
            partial[sl]                         = T[f] + scr[0][c];
            partial[(size_t)GBM * BSZ + sl]     = P[f] + scr[1][c];
            partial[(size_t)2 * GBM * BSZ + sl] = S[f] + scr[2][c];
        }
    }
}

// ---- kernel 3: WIDE finalize (256 blocks x 256 thr) + ticket combine ---------------
// Block b owns cols [b*32, b*32+32); 8 threads per column each sum 8 bm-partials
// (coalesced 128B reads), LDS-combine, per-col contr via first-order expansion
// (validated R9+), one atomicAdd + ticket; 256th block emits the scalar.
__global__ __launch_bounds__(256) void k_finalize(
        const int* __restrict__ tasks, const int* __restrict__ task_count,
        const float* __restrict__ partial, const float* __restrict__ u,
        const float* __restrict__ cls_part, int* __restrict__ hdr,
        float* __restrict__ out) {
    __shared__ float sT[8][32], sP[8][32], sS[8][32];
    __shared__ float redf[4]; __shared__ long long redn[4];
    __shared__ int lastflag;

    int* ticket = hdr;
    float* contr_total = (float*)(hdr + 1);

    int tid = threadIdx.x;
    int c = tid & 31, q = tid >> 5;      // 8 bm-groups x 32 cols
    int j = blockIdx.x * 32 + c;

    float T = 0.0f, P = 0.0f, S = 0.0f;
    #pragma unroll
    for (int k = 0; k < 8; ++k) {
        int bm = q * 8 + k;
        size_t sl = (size_t)bm * BSZ + j;
        T += partial[sl];
        P += partial[(size_t)GBM * BSZ + sl];
        S += partial[(size_t)2 * GBM * BSZ + sl];
    }
    sT[q][c] = T; sP[q][c] = P; sS[q][c] = S;
    __syncthreads();

    if (tid < 32) {
        #pragma unroll
        for (int qq = 1; qq < 8; ++qq) {
            T = (qq == 1 ? sT[0][tid] : T) + sT[qq][tid];
            P = (qq == 1 ? sP[0][tid] : P) + sP[qq][tid];
            S = (qq == 1 ? sS[0][tid] : S) + sS[qq][tid];
        }
        int jj = blockIdx.x * 32 + tid;
        int cc = task_count[tasks[jj]];
        float v = 0.0f;
        if (cc >= 2 && cc < BSZ) {
            float C = (T - P) + 1e-8f;
            v = u[jj] * ((float)(cc - 1) * logf(C) + P / C - S);
        }
        #pragma unroll
        for (int s = 1; s < 32; s <<= 1) v += __shfl_xor(v, s);
        if (tid == 0) {
            atomicAdd(contr_total, v);
            __threadfence();             // one tid0 fence per tiny block: cheap
            lastflag = (__hip_atomic_fetch_add(ticket, 1, __ATOMIC_ACQ_REL,
                                               __HIP_MEMORY_SCOPE_AGENT) == FINB - 1);
        }
    }
    __syncthreads();
    if (!lastflag) return;
    __threadfence();                     // acquire: all contr adds visible

    float cl = 0.0f;
    for (int i = tid; i < BSZ / 4; i += 256) cl += cls_part[i];
    long long cn = 0;
    if (tid < NTASK) {
        int cc = task_count[tid];
        if (cc >= 2 && cc < BSZ) cn = (long long)cc * (cc - 1);
    }
    #pragma unroll
    for (int s = 1; s < 64; s <<= 1) { cl += __shfl_xor(cl, s); cn += __shfl_xor(cn, s); }
    int w = tid >> 6, lane = tid & 63;
    if (lane == 0) { redf[w] = cl; redn[w] = cn; }
    __syncthreads();
    if (tid == 0) {
        float ct = 0.0f; long long cnt = 0;
        #pragma unroll
        for (int qq = 0; qq < 4; ++qq) { ct += redf[qq]; cnt += redn[qq]; }
        float con = __hip_atomic_load(contr_total, __ATOMIC_ACQUIRE,
                                      __HIP_MEMORY_SCOPE_AGENT);
        out[0] = 0.7f * (ct / (float)BSZ)
               + 0.3f * (cnt > 0 ? con / (float)cnt : 0.0f);
    }
}

extern "C" void kernel_launch(void* const* d_in, const int* in_sizes, int n_in,
                              void* d_out, int out_size, void* d_ws, size_t ws_size,
                              hipStream_t stream) {
    const float* logits = (const float*)d_in[0];
    const float* emb    = (const float*)d_in[1];
    const int*   labels = (const int*)d_in[2];
    const int*   tasks  = (const int*)d_in[3];
    float* out = (float*)d_out;

    char* ws = (char*)d_ws;
    // layout (4B units):
    // hdr[64]: [0]=ticket [1]=contr_total [2..58]=task_count
    // u[BSZ], cls_part[2048], partial[3*GBM*BSZ] (6 MB), E fp8[BSZ*DIM] (2 MB)
    int*   hdr      = (int*)ws;
    int*   task_cnt = hdr + 2;
    float* u        = (float*)ws + 64;
    float* cls_part = u + BSZ;
    float* partial  = cls_part + 2048;
    unsigned char* e = (unsigned char*)(partial + (size_t)3 * GBM * BSZ);

    // 3 nodes; publication via kernel boundaries (the only cheap device-wide release)
    k_prep    <<<BSZ / 4, 256, 0, stream>>>(logits, emb, labels, u, cls_part, e, hdr);
    k_negsum  <<<NTILE,   512, 0, stream>>>(e, tasks, partial, task_cnt);
    k_finalize<<<FINB,    256, 0, stream>>>(tasks, task_cnt, partial, u, cls_part,
                                            hdr, out);
}